// Round 3
// baseline (1572.380 us; speedup 1.0000x reference)
//
#include <hip/hip_runtime.h>
#include <hip/hip_bf16.h>

// StructureMapper: B=8192, R=6, D=1024, H=256, TEMP=0.5, 5 sinkhorn iters
// R3: global_load_lds staging (m97 structure, linear LDS), pre-split X,
//     merged W1 GEMM (M=98304), T1 XCD block swizzle. 2-phase 128x128x64.

typedef float f32x4 __attribute__((ext_vector_type(4)));
typedef short s16x8 __attribute__((ext_vector_type(8)));
typedef short s16x4 __attribute__((ext_vector_type(4)));

__device__ __forceinline__ unsigned short f2bf(float x) {
  unsigned int u = __float_as_uint(x);
  u += 0x7FFFu + ((u >> 16) & 1u);            // RTNE
  return (unsigned short)(u >> 16);
}
__device__ __forceinline__ float bf2f(unsigned short b) {
  return __uint_as_float(((unsigned int)b) << 16);
}

// async global->LDS, 16B per lane; LDS dest is wave-uniform base + lane*16.
__device__ __forceinline__ void gl16(const void* g, void* l) {
  __builtin_amdgcn_global_load_lds((const __attribute__((address_space(1))) void*)g,
                                   (__attribute__((address_space(3))) void*)l,
                                   16, 0, 0);
}

enum { E_NONE = 0, E_GELU = 1, E_SILUMUL = 2 };
enum { O_F32 = 0, O_PLANES = 1, O_BF16 = 2 };

// ---------------------------------------------------------------------------
// NT GEMM: C[m,n] = epi( sum_k A[m,k]*W[n,k] + bias[n] )
// A: bf16 planes (hi/lo if SPLIT) or concat(CAT: Ahi[0:256)|Acat2[256:512)).
// W: pre-split bf16 hi/lo [N,K]. SPLIT -> 3-pass error-compensated MFMA.
// Tile 128x128x64, 256 thr (4 waves 2x2), mfma_f32_16x16x32_bf16.
// Staging via global_load_lds (linear LDS layout: row r chunk c at r*64+c*8).
// T1 XCD swizzle: logical = (bid%8)*(nwg/8) + bid/8.
// ---------------------------------------------------------------------------
template<bool SPLIT, int EPI, int OUT, bool CAT>
__global__ __launch_bounds__(256, 2)
void gemm3(const short* __restrict__ Ahi, const short* __restrict__ Alo,
           const short* __restrict__ Acat2,
           const short* __restrict__ Whi, const short* __restrict__ Wlo,
           const float* __restrict__ bias,
           float* __restrict__ Cf, short* __restrict__ Chi, short* __restrict__ Clo,
           const short* __restrict__ Xhi, const short* __restrict__ Xlo,
           int K, int N)
{
  constexpr int BM = 128, BN = 128, BK = 64;
  __shared__ __attribute__((aligned(16))) short sAhi[BM * BK];
  __shared__ __attribute__((aligned(16))) short sBhi[BN * BK];
  __shared__ __attribute__((aligned(16))) short sAlo[SPLIT ? BM * BK : 8];
  __shared__ __attribute__((aligned(16))) short sBlo[SPLIT ? BN * BK : 8];

  // T1: XCD-aware swizzle (all grids have nwg % 8 == 0)
  const int nwg = gridDim.x * gridDim.y;
  const int bid = blockIdx.y * gridDim.x + blockIdx.x;
  const int logical = (bid & 7) * (nwg >> 3) + (bid >> 3);
  const int bx = logical % gridDim.x, by = logical / gridDim.x;
  const int n0 = bx * BN, m0 = by * BM;

  const int tid = threadIdx.x;
  const int lane = tid & 63, w = tid >> 6;
  const int wr = (w >> 1) * 64, wc = (w & 1) * 64;
  const int slr = lane >> 3, slc = lane & 7;     // row-in-slab, 16B chunk

  f32x4 acc[4][4] = {};

  for (int k0 = 0; k0 < K; k0 += BK) {
    __syncthreads();
    // ---- stage via global_load_lds: 16 slabs (8 rows x 64 cols) per tile ----
#pragma unroll
    for (int s4 = 0; s4 < 4; ++s4) {
      const int slab = (w << 2) + s4;            // wave-uniform, 0..15
      const int ar = slab * 8 + slr;
      const short* ga;
      if (CAT) {
        const short* base = (k0 < 256) ? Ahi : Acat2;
        const int kk = (k0 < 256) ? k0 : (k0 - 256);
        ga = base + (size_t)(m0 + ar) * 256 + kk + slc * 8;
      } else {
        ga = Ahi + (size_t)(m0 + ar) * K + k0 + slc * 8;
      }
      gl16(ga, &sAhi[slab * 512]);
      if (SPLIT) gl16(Alo + (size_t)(m0 + ar) * K + k0 + slc * 8, &sAlo[slab * 512]);
      gl16(Whi + (size_t)(n0 + ar) * K + k0 + slc * 8, &sBhi[slab * 512]);
      if (SPLIT) gl16(Wlo + (size_t)(n0 + ar) * K + k0 + slc * 8, &sBlo[slab * 512]);
    }
    __syncthreads();
    // ---- MFMA ----
#pragma unroll
    for (int kc = 0; kc < 2; ++kc) {
      const int c8 = ((kc << 2) + (lane >> 4)) * 8;
      s16x8 ah[4], al[4];
#pragma unroll
      for (int mt = 0; mt < 4; ++mt) {
        const int off = (wr + mt * 16 + (lane & 15)) * 64 + c8;
        ah[mt] = *reinterpret_cast<const s16x8*>(&sAhi[off]);
        if (SPLIT) al[mt] = *reinterpret_cast<const s16x8*>(&sAlo[off]);
      }
#pragma unroll
      for (int nt = 0; nt < 4; ++nt) {
        const int off = (wc + nt * 16 + (lane & 15)) * 64 + c8;
        s16x8 bh = *reinterpret_cast<const s16x8*>(&sBhi[off]);
        s16x8 bl = {};
        if (SPLIT) bl = *reinterpret_cast<const s16x8*>(&sBlo[off]);
#pragma unroll
        for (int mt = 0; mt < 4; ++mt) {
          acc[mt][nt] = __builtin_amdgcn_mfma_f32_16x16x32_bf16(ah[mt], bh, acc[mt][nt], 0, 0, 0);
          if (SPLIT) {
            acc[mt][nt] = __builtin_amdgcn_mfma_f32_16x16x32_bf16(ah[mt], bl, acc[mt][nt], 0, 0, 0);
            acc[mt][nt] = __builtin_amdgcn_mfma_f32_16x16x32_bf16(al[mt], bh, acc[mt][nt], 0, 0, 0);
          }
        }
      }
    }
  }
  // ---- epilogue: C/D layout col=lane&15, row=(lane>>4)*4+j (m89-verified) ----
#pragma unroll
  for (int mt = 0; mt < 4; ++mt) {
#pragma unroll
    for (int nt = 0; nt < 4; ++nt) {
      const int cc = n0 + wc + nt * 16 + (lane & 15);
      const float bv = bias ? bias[cc] : 0.f;
#pragma unroll
      for (int j = 0; j < 4; ++j) {
        const int rr = m0 + wr + mt * 16 + (lane >> 4) * 4 + j;
        float v = acc[mt][nt][j] + bv;
        const size_t idx = (size_t)rr * N + cc;
        if (EPI == E_GELU) {
          float x3 = v * v * v;
          v = 0.5f * v * (1.f + tanhf(0.7978845608028654f * (v + 0.044715f * x3)));
        } else if (EPI == E_SILUMUL) {
          float xa = bf2f((unsigned short)Xhi[idx]) + bf2f((unsigned short)Xlo[idx]);
          v *= xa / (1.f + expf(-xa));
        }
        if (OUT == O_F32) {
          Cf[idx] = v;
        } else if (OUT == O_BF16) {
          Chi[idx] = (short)f2bf(v);
        } else {
          unsigned short hh = f2bf(v);
          Chi[idx] = (short)hh;
          Clo[idx] = (short)f2bf(v - bf2f(hh));
        }
      }
    }
  }
}

// ---------------------------------------------------------------------------
// split X (both sides, contiguous [98304,1024]) fp32 -> bf16 hi/lo planes
// ---------------------------------------------------------------------------
__global__ __launch_bounds__(256)
void split_x(const float* __restrict__ xs, const float* __restrict__ xt,
             short* __restrict__ hi, short* __restrict__ lo)
{
  const size_t half4 = 12582912;   // 50331648 floats / 4 per side
  for (size_t i4 = (size_t)blockIdx.x * 256 + threadIdx.x; i4 < 25165824;
       i4 += (size_t)gridDim.x * 256) {
    const float* src = (i4 < half4) ? (xs + i4 * 4) : (xt + (i4 - half4) * 4);
    f32x4 v = *reinterpret_cast<const f32x4*>(src);
    s16x4 h4, l4;
#pragma unroll
    for (int j = 0; j < 4; ++j) {
      unsigned short h = f2bf(v[j]);
      h4[j] = (short)h;
      l4[j] = (short)f2bf(v[j] - bf2f(h));
    }
    *reinterpret_cast<s16x4*>(hi + i4 * 4) = h4;
    *reinterpret_cast<s16x4*>(lo + i4 * 4) = l4;
  }
}

// ---------------------------------------------------------------------------
// Pre-split all weights fp32 -> bf16 hi/lo. Wbil pre-transposed.
// ---------------------------------------------------------------------------
__global__ __launch_bounds__(256)
void prep_w(const float* __restrict__ W1, const float* __restrict__ Wa,
            const float* __restrict__ Wb, const float* __restrict__ Wc,
            const float* __restrict__ W2, const float* __restrict__ Wbil,
            const float* __restrict__ Wa1, const float* __restrict__ Wa2,
            short* __restrict__ hi, short* __restrict__ lo)
{
  int e0 = (blockIdx.x * 256 + threadIdx.x) * 4;
  const float* src; int local; bool tr = false;
  if      (e0 < 262144)  { src = W1;   local = e0; }
  else if (e0 < 393216)  { src = Wa;   local = e0 - 262144; }
  else if (e0 < 524288)  { src = Wb;   local = e0 - 393216; }
  else if (e0 < 655360)  { src = Wc;   local = e0 - 524288; }
  else if (e0 < 720896)  { src = W2;   local = e0 - 655360; }
  else if (e0 < 786432)  { src = Wbil; local = e0 - 720896; tr = true; }
  else if (e0 < 1048576) { src = Wa1;  local = e0 - 786432; }
  else                   { src = Wa2;  local = e0 - 1048576; }
  float v[4];
  if (tr) {
#pragma unroll
    for (int t = 0; t < 4; ++t) {
      int li = local + t;
      int n = li >> 8, hh = li & 255;
      v[t] = src[hh * 256 + n];        // WbilT[n][h] = Wbil[h][n]
    }
  } else {
    f32x4 tv = *reinterpret_cast<const f32x4*>(src + local);
    v[0] = tv[0]; v[1] = tv[1]; v[2] = tv[2]; v[3] = tv[3];
  }
#pragma unroll
  for (int t = 0; t < 4; ++t) {
    unsigned short h = f2bf(v[t]);
    hi[e0 + t] = (short)h;
    lo[e0 + t] = (short)f2bf(v[t] - bf2f(h));
  }
}

// ---------------------------------------------------------------------------
// RMSNorm on hi/lo planes, L=256. One wave per row, 4 rows/block.
// ---------------------------------------------------------------------------
__global__ __launch_bounds__(256)
void rmsnorm_planes256(short* __restrict__ xhi, short* __restrict__ xlo,
                       const float* __restrict__ g)
{
  int wid = threadIdx.x >> 6, lane = threadIdx.x & 63;
  size_t row = (size_t)blockIdx.x * 4 + wid;
  short* ph = xhi + row * 256 + lane * 4;
  short* pl = xlo + row * 256 + lane * 4;
  s16x4 h4 = *reinterpret_cast<const s16x4*>(ph);
  s16x4 l4 = *reinterpret_cast<const s16x4*>(pl);
  float v[4]; float ss = 0.f;
#pragma unroll
  for (int j = 0; j < 4; ++j) {
    v[j] = bf2f((unsigned short)h4[j]) + bf2f((unsigned short)l4[j]);
    ss += v[j] * v[j];
  }
#pragma unroll
  for (int o = 32; o > 0; o >>= 1) ss += __shfl_xor(ss, o);
  float s = rsqrtf(ss * (1.f / 256.f) + 1e-6f);
  f32x4 gg = *reinterpret_cast<const f32x4*>(g + lane * 4);
#pragma unroll
  for (int j = 0; j < 4; ++j) {
    float o = v[j] * s * gg[j];
    unsigned short hh = f2bf(o);
    h4[j] = (short)hh;
    l4[j] = (short)f2bf(o - bf2f(hh));
  }
  *reinterpret_cast<s16x4*>(ph) = h4;
  *reinterpret_cast<s16x4*>(pl) = l4;
}

// ---------------------------------------------------------------------------
// RMSNorm fp32 in-place, L=1024 (answer). One wave per row, 4 rows/block.
// ---------------------------------------------------------------------------
__global__ __launch_bounds__(256)
void rmsnorm_f32_1024(float* __restrict__ x, const float* __restrict__ g)
{
  int wid = threadIdx.x >> 6, lane = threadIdx.x & 63;
  size_t row = (size_t)blockIdx.x * 4 + wid;
  float* p = x + row * 1024;
  f32x4 v[4];
  float ss = 0.f;
#pragma unroll
  for (int i = 0; i < 4; ++i) {
    v[i] = *reinterpret_cast<const f32x4*>(p + (i * 64 + lane) * 4);
    ss += v[i][0] * v[i][0] + v[i][1] * v[i][1] + v[i][2] * v[i][2] + v[i][3] * v[i][3];
  }
#pragma unroll
  for (int o = 32; o > 0; o >>= 1) ss += __shfl_xor(ss, o);
  float s = rsqrtf(ss * (1.f / 1024.f) + 1e-6f);
#pragma unroll
  for (int i = 0; i < 4; ++i) {
    f32x4 gg = *reinterpret_cast<const f32x4*>(g + (i * 64 + lane) * 4);
    f32x4 o4;
#pragma unroll
    for (int j = 0; j < 4; ++j) o4[j] = v[i][j] * s * gg[j];
    *reinterpret_cast<f32x4*>(p + (i * 64 + lane) * 4) = o4;
  }
}

// ---------------------------------------------------------------------------
// Per-batch sinkhorn (fp32 exact). 1 wave per batch.
// ---------------------------------------------------------------------------
__global__ __launch_bounds__(64)
void sinkhorn_k(const float* __restrict__ P,
                const short* __restrict__ Sehi, const short* __restrict__ Selo,
                const short* __restrict__ Tehi, const short* __restrict__ Telo,
                const float* __restrict__ bbil,
                const float* __restrict__ Wc1, const float* __restrict__ bc1,
                float* __restrict__ omap, float* __restrict__ omapped,
                short* __restrict__ omappedb, float* __restrict__ oconf)
{
  int b = blockIdx.x, lane = threadIdx.x;
  __shared__ __attribute__((aligned(16))) float sP[6 * 260];
  __shared__ __attribute__((aligned(16))) float sT[6 * 260];
  __shared__ __attribute__((aligned(16))) float sS[6 * 260];
  const f32x4* gp = reinterpret_cast<const f32x4*>(P + (size_t)b * 1536);
#pragma unroll
  for (int i0 = 0; i0 < 6; ++i0) {
    int i = i0 * 64 + lane;
    int r = i >> 6, c = i & 63;
    *reinterpret_cast<f32x4*>(&sP[r * 260 + c * 4]) = gp[i];
    size_t e = (size_t)b * 1536 + i * 4;
    s16x4 th = *reinterpret_cast<const s16x4*>(Tehi + e);
    s16x4 tl = *reinterpret_cast<const s16x4*>(Telo + e);
    s16x4 sh = *reinterpret_cast<const s16x4*>(Sehi + e);
    s16x4 sl = *reinterpret_cast<const s16x4*>(Selo + e);
#pragma unroll
    for (int j = 0; j < 4; ++j) {
      sT[r * 260 + c * 4 + j] = bf2f((unsigned short)th[j]) + bf2f((unsigned short)tl[j]);
      sS[r * 260 + c * 4 + j] = bf2f((unsigned short)sh[j]) + bf2f((unsigned short)sl[j]);
    }
  }
  __syncthreads();
  int i = lane / 6, j = lane - i * 6;   // valid for lane<36
  float la = 0.f;
  if (lane < 36) {
    const float* pr = &sP[i * 260];
    const float* tr = &sT[j * 260];
    float d = 0.f;
    for (int k = 0; k < 256; ++k) d = fmaf(pr[k], tr[k], d);
    la = (d + bbil[0]) * 2.0f;          // /TEMP, TEMP=0.5
  }
#pragma unroll
  for (int it = 0; it < 5; ++it) {
    float m = -1e30f, s = 0.f;
#pragma unroll
    for (int t = 0; t < 6; ++t) m = fmaxf(m, __shfl(la, i * 6 + t));
#pragma unroll
    for (int t = 0; t < 6; ++t) s += expf(__shfl(la, i * 6 + t) - m);
    la -= m + logf(s);
    m = -1e30f; s = 0.f;
#pragma unroll
    for (int t = 0; t < 6; ++t) m = fmaxf(m, __shfl(la, t * 6 + j));
#pragma unroll
    for (int t = 0; t < 6; ++t) s += expf(__shfl(la, t * 6 + j) - m);
    la -= m + logf(s);
  }
  float mp = (lane < 36) ? expf(la) : 0.f;
  if (lane < 36) omap[(size_t)b * 36 + lane] = mp;
  float mm[36];
#pragma unroll
  for (int t = 0; t < 36; ++t) mm[t] = __shfl(mp, t);
  float asum = 0.f;
#pragma unroll
  for (int ii = 0; ii < 6; ++ii) {
    f32x4 av = {0.f, 0.f, 0.f, 0.f};
#pragma unroll
    for (int k = 0; k < 6; ++k) {
      f32x4 tv = *reinterpret_cast<const f32x4*>(&sT[k * 260 + lane * 4]);
      av += tv * mm[ii * 6 + k];
    }
    f32x4 sv = *reinterpret_cast<const f32x4*>(&sS[ii * 260 + lane * 4]);
    size_t e = (size_t)b * 1536 + ii * 256 + lane * 4;
    *reinterpret_cast<f32x4*>(omapped + e) = av;
    s16x4 mb;
#pragma unroll
    for (int jj = 0; jj < 4; ++jj) mb[jj] = (short)f2bf(av[jj]);
    *reinterpret_cast<s16x4*>(omappedb + e) = mb;
    asum += fabsf(av[0] - sv[0]) + fabsf(av[1] - sv[1]) +
            fabsf(av[2] - sv[2]) + fabsf(av[3] - sv[3]);
  }
#pragma unroll
  for (int o = 32; o > 0; o >>= 1) asum += __shfl_xor(asum, o);
  if (lane == 0) {
    float ci = asum * (1.f / 1536.f);
    float z = ci * Wc1[0] + bc1[0];
    oconf[b] = 1.f / (1.f + expf(-z));
  }
}

// ---------------------------------------------------------------------------
extern "C" void kernel_launch(void* const* d_in, const int* in_sizes, int n_in,
                              void* d_out, int out_size, void* d_ws, size_t ws_size,
                              hipStream_t stream)
{
  const float* src_roles = (const float*)d_in[0];
  const float* tgt_roles = (const float*)d_in[1];
  const float* W1   = (const float*)d_in[2];
  const float* b1   = (const float*)d_in[3];
  const float* g1   = (const float*)d_in[4];
  const float* Wa   = (const float*)d_in[5];
  const float* Wb   = (const float*)d_in[6];
  const float* Wc   = (const float*)d_in[7];
  const float* W2   = (const float*)d_in[8];
  const float* b2   = (const float*)d_in[9];
  const float* Wbil = (const float*)d_in[10];
  const float* bbil = (const float*)d_in[11];
  const float* Wa1  = (const float*)d_in[12];
  const float* ba1  = (const float*)d_in[13];
  const float* Wa2  = (const float*)d_in[14];
  const float* ba2  = (const float*)d_in[15];
  const float* g2   = (const float*)d_in[16];
  const float* Wc1  = (const float*)d_in[17];
  const float* bc1  = (const float*)d_in[18];

  float* out = (float*)d_out;
  float* o_answer  = out;                  // 49152*1024 f32
  float* o_mapping = out + 50331648;       // 8192*36
  float* o_mapped  = out + 50626560;       // 49152*256
  float* o_conf    = out + 63209472;       // 8192
  // per-side xa/t planes stashed in the (not-yet-written) answer region:
  short* xa_hi = (short*)out;              // 25,165,824 each; 4 planes = region
  short* xa_lo = xa_hi + 25165824;
  short* t_hi  = xa_lo + 25165824;
  short* t_lo  = t_hi + 25165824;

  short* S = (short*)d_ws;
  // phase 1 (until W1 done): X planes [98304,1024]
  short* Xp_hi = S;                        // 100,663,296
  short* Xp_lo = S + 100663296;            // 100,663,296
  // phase 2 (after W1): aliases into the X-plane region
  short* u_hi  = S + 0;
  short* u_lo  = S + 12582912;
  short* eS_hi = S + 25165824;
  short* eS_lo = S + 37748736;
  short* eT_hi = S + 50331648;
  short* eT_lo = S + 62914560;
  short* act   = S + 75497472;             // 25,165,824
  short* mapb  = S + 100663296;            // 12,582,912
  // non-aliased tail:
  float* P     = (float*)(S + 201326592);  // 12,582,912 f32
  short* whi   = S + 226492416;            // 1,572,864
  short* wlo   = S + 228065280;
  short* h_hi  = S + 229638144;            // 25,165,824 ([98304,256])
  short* h_lo  = S + 254803968;            // ends at 279,969,792 shorts (~534 MB)

  const int oW1 = 0, oWa = 262144, oWb = 393216, oWc = 524288, oW2 = 655360,
            oWbt = 720896, oWa1 = 786432, oWa2 = 1048576;
  const short* NS = nullptr; const float* NF = nullptr;
  float* NFo = nullptr; short* NSo = nullptr;

  hipLaunchKernelGGL(prep_w, dim3(1536), dim3(256), 0, stream,
                     W1, Wa, Wb, Wc, W2, Wbil, Wa1, Wa2, whi, wlo);
  hipLaunchKernelGGL(split_x, dim3(2048), dim3(256), 0, stream,
                     src_roles, tgt_roles, Xp_hi, Xp_lo);

  // h = X @ W1^T + b1 -> planes, merged both sides: [98304,256], K=1024
  hipLaunchKernelGGL((gemm3<true, E_NONE, O_PLANES, false>), dim3(2, 768), dim3(256), 0, stream,
                     Xp_hi, Xp_lo, NS, whi + oW1, wlo + oW1, b1,
                     NFo, h_hi, h_lo, NS, NS, 1024, 256);
  hipLaunchKernelGGL(rmsnorm_planes256, dim3(24576), dim3(256), 0, stream, h_hi, h_lo, g1);

  for (int s = 0; s < 2; ++s) {
    const short* hs_hi = h_hi + (size_t)s * 49152 * 256;
    const short* hs_lo = h_lo + (size_t)s * 49152 * 256;
    short* e_hi = (s == 0) ? eS_hi : eT_hi;
    short* e_lo = (s == 0) ? eS_lo : eT_lo;
    // xa = h @ Wa^T -> planes   [49152,512], K=256
    hipLaunchKernelGGL((gemm3<true, E_NONE, O_PLANES, false>), dim3(4, 384), dim3(256), 0, stream,
                       hs_hi, hs_lo, NS, whi + oWa, wlo + oWa, NF,
                       NFo, xa_hi, xa_lo, NS, NS, 256, 512);
    // t = silu(xa) * (h @ Wb^T) -> planes
    hipLaunchKernelGGL((gemm3<true, E_SILUMUL, O_PLANES, false>), dim3(4, 384), dim3(256), 0, stream,
                       hs_hi, hs_lo, NS, whi + oWb, wlo + oWb, NF,
                       NFo, t_hi, t_lo, xa_hi, xa_lo, 256, 512);
    // u = t @ Wc^T -> planes    [49152,256], K=512
    hipLaunchKernelGGL((gemm3<true, E_NONE, O_PLANES, false>), dim3(2, 384), dim3(256), 0, stream,
                       t_hi, t_lo, NS, whi + oWc, wlo + oWc, NF,
                       NFo, u_hi, u_lo, NS, NS, 512, 256);
    // enc = u @ W2^T + b2 -> planes
    hipLaunchKernelGGL((gemm3<true, E_NONE, O_PLANES, false>), dim3(2, 384), dim3(256), 0, stream,
                       u_hi, u_lo, NS, whi + oW2, wlo + oW2, b2,
                       NFo, e_hi, e_lo, NS, NS, 256, 256);
  }
  // P = encS @ WbilT -> f32
  hipLaunchKernelGGL((gemm3<true, E_NONE, O_F32, false>), dim3(2, 384), dim3(256), 0, stream,
                     eS_hi, eS_lo, NS, whi + oWbt, wlo + oWbt, NF,
                     P, NSo, NSo, NS, NS, 256, 256);
  hipLaunchKernelGGL(sinkhorn_k, dim3(8192), dim3(64), 0, stream,
                     P, eS_hi, eS_lo, eT_hi, eT_lo, bbil, Wc1, bc1,
                     o_mapping, o_mapped, mapb, o_conf);
  // act = gelu([mapped | encT] @ Wa1^T + ba1) -> bf16   [49152,512], K=512
  hipLaunchKernelGGL((gemm3<false, E_GELU, O_BF16, true>), dim3(4, 384), dim3(256), 0, stream,
                     mapb, NS, eT_hi, whi + oWa1, wlo + oWa1, ba1,
                     NFo, act, NSo, NS, NS, 512, 512);
  // answer = act @ Wa2^T + ba2 -> f32  [49152,1024], K=512 (overwrites stash)
  hipLaunchKernelGGL((gemm3<false, E_NONE, O_F32, false>), dim3(8, 384), dim3(256), 0, stream,
                     act, NS, NS, whi + oWa2, wlo + oWa2, ba2,
                     o_answer, NSo, NSo, NS, NS, 512, 1024);
  hipLaunchKernelGGL(rmsnorm_f32_1024, dim3(12288), dim3(256), 0, stream, o_answer, g2);
}